// Round 20
// baseline (900.813 us; speedup 1.0000x reference)
//
#include <hip/hip_runtime.h>
#include <cstdio>

// MoE top-2 FFN: B=4,S=2048,D=1024 -> T=8192 tokens; E=8, H=4096, K_TOP=2.
// Round 20: r19 (776us best) with ONE change: gemm2_k __launch_bounds__
// (256,4) -> (256,5). LDS (32KB) admits 5 blocks/CU; VGPR cap at 5 waves/EU
// is ~102 >> the kernel's 60 (no spill risk — r7/r9's failure mode was caps
// BELOW need). +25% co-resident waves to hide the 2-phase per-tile drain —
// cross-block TLP is the only lever that has consistently paid in this
// family. g1w2 stays (256,4): its 33792B smem union caps it at 4 blocks/CU.

#define T_TOK 8192
#define DIM   1024
#define NEXP  8
#define HID   4096
#define MAXR  17408  // 16384 rows + 8 experts * up-to-127 pad, mult of 512

typedef float          f32x4   __attribute__((ext_vector_type(4)));
typedef short          bf16x8  __attribute__((ext_vector_type(8)));
typedef unsigned short u16x8   __attribute__((ext_vector_type(8)));
typedef unsigned short u16x4   __attribute__((ext_vector_type(4)));

static __device__ __forceinline__ unsigned short f2bf(float f) {
  unsigned int u = __builtin_bit_cast(unsigned int, f);
  u = (u + 0x7FFFu + ((u >> 16) & 1u)) >> 16;   // round-nearest-even (finite inputs)
  return (unsigned short)u;
}

// async global->LDS, 16B per lane; LDS dest = wave-uniform base + lane*16,
// global source is PER-LANE (enables token-indirect A staging)
static __device__ __forceinline__ void gl16(const void* g, void* l) {
  __builtin_amdgcn_global_load_lds(
      (const __attribute__((address_space(1))) unsigned int*)g,
      (__attribute__((address_space(3))) unsigned int*)l,
      16, 0, 0);
}

// ---------------- transpose + fp32->bf16, LDS-staged 128x128 tile ------------
static __device__ __forceinline__ void transpose_body(const float* __restrict__ W,
                                                      unsigned short* __restrict__ WT,
                                                      int R, int C, int bx, int by, int e,
                                                      unsigned int* tl) {
  int t = threadIdx.x;
  int r0 = by * 128, c0 = bx * 128;
  const float* src = W + (size_t)e * R * C + (size_t)r0 * C + c0;
  int cg = t & 31, ph = t >> 5;                  // col-group (x4 floats), p-high
  int c4 = cg * 4;
#pragma unroll
  for (int u = 0; u < 8; ++u) {
    int p = u * 8 + ph;                          // row-pair 0..63
    float4 f0 = *(const float4*)(src + (size_t)(2 * p) * C + c4);
    float4 f1 = *(const float4*)(src + (size_t)(2 * p + 1) * C + c4);
    unsigned int v0 = ((unsigned)f2bf(f1.x) << 16) | f2bf(f0.x);
    unsigned int v1 = ((unsigned)f2bf(f1.y) << 16) | f2bf(f0.y);
    unsigned int v2 = ((unsigned)f2bf(f1.z) << 16) | f2bf(f0.z);
    unsigned int v3 = ((unsigned)f2bf(f1.w) << 16) | f2bf(f0.w);
    *(uint4*)(tl + p * 132 + c4) = make_uint4(v0, v1, v2, v3);
  }
  __syncthreads();
  int rg = t & 15, ch = t >> 4;                  // row-group (x8 rows), col-high
  unsigned short* dst = WT + (size_t)e * R * C + (size_t)c0 * R + r0 + rg * 8;
#pragma unroll
  for (int u = 0; u < 8; ++u) {
    int c = ch + u * 16;
    u16x8 o;
#pragma unroll
    for (int j = 0; j < 4; ++j) {
      unsigned int v = tl[(rg * 4 + j) * 132 + c];
      o[2 * j]     = (unsigned short)(v & 0xffff);
      o[2 * j + 1] = (unsigned short)(v >> 16);
    }
    *(u16x8*)(dst + (size_t)c * R) = o;
  }
}

static __device__ __forceinline__ void router_body(int blk, const float* __restrict__ x,
                                                   const float* __restrict__ Wr,
                                                   const float* __restrict__ br,
                                                   int* __restrict__ meta,
                                                   int2* __restrict__ top_i,
                                                   float2* __restrict__ top_w) {
  int lane = threadIdx.x & 63;
  int wid  = threadIdx.x >> 6;
  int t = blk * 4 + wid;
  const float* xp = x + (size_t)t * DIM + lane * 16;
  float acc[NEXP];
#pragma unroll
  for (int e = 0; e < NEXP; ++e) acc[e] = 0.f;
#pragma unroll
  for (int j = 0; j < 16; j += 4) {
    float4 xv = *(const float4*)(xp + j);
    const float* wp = Wr + (size_t)(lane * 16 + j) * NEXP;
#pragma unroll
    for (int jj = 0; jj < 4; ++jj) {
      float xs = jj == 0 ? xv.x : jj == 1 ? xv.y : jj == 2 ? xv.z : xv.w;
      float4 w0 = *(const float4*)(wp + jj * NEXP);
      float4 w1 = *(const float4*)(wp + jj * NEXP + 4);
      acc[0] += xs * w0.x; acc[1] += xs * w0.y; acc[2] += xs * w0.z; acc[3] += xs * w0.w;
      acc[4] += xs * w1.x; acc[5] += xs * w1.y; acc[6] += xs * w1.z; acc[7] += xs * w1.w;
    }
  }
#pragma unroll
  for (int off = 32; off > 0; off >>= 1) {
#pragma unroll
    for (int e = 0; e < NEXP; ++e) acc[e] += __shfl_xor(acc[e], off);
  }
  if (lane == 0) {
    float l[NEXP];
#pragma unroll
    for (int e = 0; e < NEXP; ++e) l[e] = acc[e] + br[e];
    int e1 = 0;
#pragma unroll
    for (int e = 1; e < NEXP; ++e) if (l[e] > l[e1]) e1 = e;      // ties -> lower idx
    int e2 = (e1 == 0) ? 1 : 0;
#pragma unroll
    for (int e = 0; e < NEXP; ++e) if (e != e1 && l[e] > l[e2]) e2 = e;
    float g  = expf(l[e2] - l[e1]);              // softmax over top-2 == renorm of full softmax
    float w1 = 1.f / (1.f + g);
    top_i[t] = make_int2(e1, e2);
    top_w[t] = make_float2(w1, 1.f - w1);
    atomicAdd(&meta[e1], 1);
    atomicAdd(&meta[e2], 1);
  }
}

// ---- prep1: [0,2048) W1 transpose, [2048,4096) router, [4096,4164) fill,
//      [4164,6212) x->bf16 convert  (W2 transpose lives in g1w2_k) -----------
__global__ __launch_bounds__(256) void prep1_k(const float* __restrict__ W1,
                                               unsigned short* __restrict__ W1bT,
                                               const float* __restrict__ x,
                                               const float* __restrict__ Wr,
                                               const float* __restrict__ br,
                                               int* __restrict__ meta,
                                               int2* __restrict__ top_i,
                                               float2* __restrict__ top_w,
                                               int* __restrict__ tok_of_row,
                                               float* __restrict__ wt_of_row,
                                               unsigned short* __restrict__ xb) {
  __shared__ __align__(16) unsigned int tl[64 * 132];   // 33792 B
  int id = blockIdx.x;
  if (id < 2048) {                               // W1[e][D][H] -> [e][H][D]
    int rem = id & 255;                          // 8 by x 32 bx per expert
    transpose_body(W1, W1bT, DIM, HID, rem & 31, rem >> 5, id >> 8, tl);
  } else if (id < 4096) {
    router_body(id - 2048, x, Wr, br, meta, top_i, top_w);
  } else if (id < 4164) {
    int i = (id - 4096) * 256 + threadIdx.x;     // 68*256 == MAXR exactly
    if (i < MAXR) { tok_of_row[i] = 0; wt_of_row[i] = 0.f; }
  } else {                                       // xb = bf16(x), streaming
    size_t o = (size_t)(id - 4164) * 4096 + (size_t)threadIdx.x * 16;
#pragma unroll
    for (int h = 0; h < 2; ++h) {
      float4 a = *(const float4*)(x + o + h * 8);
      float4 b = *(const float4*)(x + o + h * 8 + 4);
      u16x8 v;
      v[0] = f2bf(a.x); v[1] = f2bf(a.y); v[2] = f2bf(a.z); v[3] = f2bf(a.w);
      v[4] = f2bf(b.x); v[5] = f2bf(b.y); v[6] = f2bf(b.z); v[7] = f2bf(b.w);
      *(u16x8*)(xb + o + h * 8) = v;
    }
  }
}

// -------- prefix: padded (x128) offsets ------------------------------------
__global__ void prefix_k(int* __restrict__ meta) {
  if (threadIdx.x == 0) {
    int s = 0;
#pragma unroll
    for (int e = 0; e < NEXP; ++e) {
      meta[16 + e] = s;                          // poff[e]
      s += (meta[e] + 127) & ~127;
    }
    meta[24] = s;                                // poff[8]
    meta[25] = s;                                // total_padded (<= MAXR always)
  }
}

// ---------------- scatter: token -> packed expert row ------------------------
__global__ __launch_bounds__(256) void scatter_k(const int2* __restrict__ top_i,
                                                 const float2* __restrict__ top_w,
                                                 int* __restrict__ meta,
                                                 int* __restrict__ row_of,
                                                 int* __restrict__ tok_of_row,
                                                 float* __restrict__ wt_of_row) {
  int t = blockIdx.x * 256 + threadIdx.x;
  int2  ei = top_i[t];
  float2 w = top_w[t];
  int p = atomicAdd(&meta[8 + ei.x], 1);
  int r = meta[16 + ei.x] + p;
  tok_of_row[r] = t; wt_of_row[r] = w.x; row_of[t * 2] = r;
  p = atomicAdd(&meta[8 + ei.y], 1);
  r = meta[16 + ei.y] + p;
  tok_of_row[r] = t; wt_of_row[r] = w.y; row_of[t * 2 + 1] = r;
}

// ---------------- GEMM body (r16-verbatim, id passed in) ---------------------
// A: bf16 (xb token-indirect for GEMM1, packed hbuf for GEMM2), gl16-staged
// into [128 rows][8 slots x 8] XOR-swizzled regions.  Bt: [E][NTOT][KTOT] bf16.
// 128x128 tile, BK=64, 4 waves, 32KB LDS, XCD-chunked 4x4 supertiles, pad-skip.
// EPI 0: h = bf16(gelu(acc+b1))   EPI 1: atomicAdd out[tok] += (acc+b2)*wt

template <int KTOT, int NTOT, int EPI, bool INDIR>
static __device__ __forceinline__ void gemm_body(int rawid,
                                                 const unsigned short* __restrict__ A,
                                                 const unsigned short* __restrict__ Bt,
                                                 const float* __restrict__ bias,
                                                 const int* __restrict__ meta,
                                                 const float* __restrict__ wt_of_row,
                                                 const int* __restrict__ tok_of_row,
                                                 void* __restrict__ Cout,
                                                 unsigned short* lds) {
  constexpr int NN  = NTOT / 128;                // 32 or 8
  constexpr int NXB = MAXR / 128;                // 136 row tiles
  constexpr int NWG = NXB * NN;                  // 4352 or 1088, both % 8 == 0
  constexpr int NSR = NXB / 4;                   // 34 row supertiles
  constexpr int NKT = KTOT / 64;                 // 16 or 64

  int id = (rawid & 7) * (NWG / 8) + (rawid >> 3);
  int sid = id >> 4, sub = id & 15;
  int row0 = ((sid % NSR) * 4 + (sub & 3)) * 128;
  int n0   = ((sid / NSR) * 4 + (sub >> 2)) * 128;
  if (row0 >= meta[25]) return;                  // beyond padded total (block-uniform)
  int e = 0;
  while (meta[17 + e] <= row0) ++e;              // tiles never straddle experts
  if (row0 - meta[16 + e] >= meta[e]) return;    // all-pad tile: skip (wt==0 gates EPI1)
  const unsigned short* Bp = Bt + (size_t)e * NTOT * KTOT;

  int tid = threadIdx.x;
  int lane = tid & 63, wid = tid >> 6;
  int wm = wid >> 1, wn = wid & 1;               // 2x2 waves, each owns 64x64 of C

  // staging (T2 write side): source col-slot s = (tid&7) ^ ((tid>>3)&7)
  int s = (tid & 7) ^ ((tid >> 3) & 7);
  const unsigned short* pA[4];
#pragma unroll
  for (int i = 0; i < 4; ++i) {
    int r = row0 + (tid >> 3) + i * 32;
    if constexpr (INDIR) {
      pA[i] = A + (size_t)tok_of_row[r] * KTOT + s * 8;   // pad rows: tok 0 (valid)
    } else {
      pA[i] = A + (size_t)r * KTOT + s * 8;
    }
  }
  const unsigned short* pB = Bp + (size_t)(n0 + (tid >> 3)) * KTOT + s * 8;

  // fragment reads (T2 read side): slot = (kk*4+g) ^ (am&7)
  int am = lane & 15, g = lane >> 4;
  int sw0 = ((0 * 4 + g) ^ (am & 7)) * 8;
  int sw1 = ((1 * 4 + g) ^ (am & 7)) * 8;
  int aRow = (wm * 64 + am) * 64;                // + i*1024 per fragment
  int bRow = 8192 + (wn * 64 + am) * 64;         // + j*1024 per fragment

  f32x4 acc[4][4];
#pragma unroll
  for (int i = 0; i < 4; ++i)
#pragma unroll
    for (int j = 0; j < 4; ++j) acc[i][j] = (f32x4){0.f, 0.f, 0.f, 0.f};

  for (int kt = 0; kt < NKT; ++kt) {
    __syncthreads();                             // prev compute done before overwrite
#pragma unroll
    for (int i = 0; i < 4; ++i) {
      gl16(pA[i] + kt * 64, lds + i * 2048 + tid * 8);
      gl16(pB + (size_t)(i * 32) * KTOT + kt * 64, lds + 8192 + i * 2048 + tid * 8);
    }
    __syncthreads();                             // compiler drains vmcnt before barrier
#pragma unroll
    for (int kk = 0; kk < 2; ++kk) {
      int sw = kk ? sw1 : sw0;
      bf16x8 af[4], bv[4];
#pragma unroll
      for (int i = 0; i < 4; ++i)
        af[i] = *(const bf16x8*)(lds + aRow + i * 1024 + sw);
#pragma unroll
      for (int j = 0; j < 4; ++j)
        bv[j] = *(const bf16x8*)(lds + bRow + j * 1024 + sw);
#pragma unroll
      for (int i = 0; i < 4; ++i)
#pragma unroll
        for (int j = 0; j < 4; ++j)
          acc[i][j] = __builtin_amdgcn_mfma_f32_16x16x32_bf16(af[i], bv[j], acc[i][j], 0, 0, 0);
    }
  }

  // epilogue.  C/D: col n = lane&15, row m = (lane>>4)*4 + reg  (validated)
  int rbase = row0 + wm * 64 + (g << 2);
  int nbase = n0 + wn * 64 + am;
  if constexpr (EPI == 0) {
    unsigned short* Hp = (unsigned short*)Cout;
    const float* bp = bias + (size_t)e * NTOT;
#pragma unroll
    for (int i = 0; i < 4; ++i)
#pragma unroll
      for (int j = 0; j < 4; ++j) {
        int n = nbase + j * 16;
        float bv = bp[n];
#pragma unroll
        for (int gg = 0; gg < 4; ++gg) {
          int m = rbase + i * 16 + gg;
          float v = acc[i][j][gg] + bv;
          v = 0.5f * v * (1.f + erff(v * 0.70710678118654752f));   // exact gelu
          Hp[(size_t)m * NTOT + n] = f2bf(v);
        }
      }
  } else {
    float* Op = (float*)Cout;
    const float* bp = bias + (size_t)e * NTOT;
#pragma unroll
    for (int i = 0; i < 4; ++i)
#pragma unroll
      for (int gg = 0; gg < 4; ++gg) {
        int m = rbase + i * 16 + gg;
        float wt = wt_of_row[m];
        if (wt != 0.f) {                         // pad rows excluded (wt exactly 0)
          float* orow = Op + (size_t)tok_of_row[m] * DIM;
#pragma unroll
          for (int j = 0; j < 4; ++j) {
            int n = nbase + j * 16;
            atomicAdd(orow + n, (acc[i][j][gg] + bp[n]) * wt);
          }
        }
      }
  }
}

// ---------------- fused GEMM1 + W2-transpose --------------------------------
// 6400 blocks: p%3==2 (p<6144) -> W2 transpose block p/3 (2048 of them,
// interleaved to co-schedule with GEMM1 and fill its stall bubbles);
// otherwise GEMM1 block (4352). Shared-mem union: 33792 B -> 4 blocks/CU.
__global__ __launch_bounds__(256, 4) void g1w2_k(const unsigned short* __restrict__ xb,
                                                 const unsigned short* __restrict__ W1bT,
                                                 const float* __restrict__ W2,
                                                 unsigned short* __restrict__ W2bT,
                                                 const float* __restrict__ b1,
                                                 const int* __restrict__ meta,
                                                 const float* __restrict__ wt_of_row,
                                                 const int* __restrict__ tok_of_row,
                                                 unsigned short* __restrict__ hbuf) {
  __shared__ __align__(16) unsigned char smem[64 * 132 * 4];   // 33792 B union
  int p = blockIdx.x;
  if (p < 6144 && (p % 3) == 2) {
    int id2 = p / 3;                             // 0..2047
    int rem = id2 & 255;                         // 32 by x 8 bx per expert
    transpose_body(W2, W2bT, HID, DIM, rem & 7, rem >> 3, id2 >> 8,
                   (unsigned int*)smem);
  } else {
    int rawid = (p < 6144) ? (p - p / 3) : (p - 2048);   // 0..4351, monotone
    gemm_body<DIM, HID, 0, true>(rawid, xb, W1bT, b1, meta, wt_of_row,
                                 tok_of_row, (void*)hbuf,
                                 (unsigned short*)smem);
  }
}

// ---------------- GEMM2 kernel: 32KB LDS -> 5 blocks/CU admissible -----------
__global__ __launch_bounds__(256, 5) void gemm2_k(const unsigned short* __restrict__ hbuf,
                                                  const unsigned short* __restrict__ W2bT,
                                                  const float* __restrict__ b2,
                                                  const int* __restrict__ meta,
                                                  const float* __restrict__ wt_of_row,
                                                  const int* __restrict__ tok_of_row,
                                                  float* __restrict__ out) {
  __shared__ __align__(16) unsigned short lds[16384];   // 32 KiB
  gemm_body<HID, DIM, 1, false>((int)blockIdx.x, hbuf, W2bT, b2, meta,
                                wt_of_row, tok_of_row, (void*)out, lds);
}

extern "C" void kernel_launch(void* const* d_in, const int* in_sizes, int n_in,
                              void* d_out, int out_size, void* d_ws, size_t ws_size,
                              hipStream_t stream) {
  const float* x  = (const float*)d_in[0];
  const float* Wr = (const float*)d_in[1];
  const float* br = (const float*)d_in[2];
  const float* W1 = (const float*)d_in[3];
  const float* b1 = (const float*)d_in[4];
  const float* W2 = (const float*)d_in[5];
  const float* b2 = (const float*)d_in[6];
  float* out = (float*)d_out;

  char* base = (char*)d_ws;
  size_t off = 0;
  auto carve = [&](size_t bytes) -> void* {
    void* r = base + off;
    off = (off + bytes + 255) & ~(size_t)255;
    return r;
  };
  int*            meta       = (int*)carve(26 * 4);
  int2*           top_i      = (int2*)carve((size_t)T_TOK * 8);
  float2*         top_w      = (float2*)carve((size_t)T_TOK * 8);
  int*            row_of     = (int*)carve((size_t)T_TOK * 2 * 4);
  int*            tok_of_row = (int*)carve((size_t)MAXR * 4);
  float*          wt_of_row  = (float*)carve((size_t)MAXR * 4);
  unsigned short* xb         = (unsigned short*)carve((size_t)T_TOK * DIM * 2);
  unsigned short* W1bT       = (unsigned short*)carve((size_t)NEXP * DIM * HID * 2);
  unsigned short* W2bT       = (unsigned short*)carve((size_t)NEXP * DIM * HID * 2);
  unsigned short* hbuf       = (unsigned short*)carve((size_t)MAXR * HID * 2);
  if (off > ws_size) {
    fprintf(stderr, "kernel_launch: ws_size too small: need %zu have %zu\n", off, ws_size);
    return;
  }

  hipMemsetAsync(meta, 0, 26 * 4, stream);
  hipMemsetAsync(out, 0, (size_t)out_size * 4, stream);   // GEMM2 atomicAdds into out
  hipLaunchKernelGGL(prep1_k, dim3(6212), dim3(256), 0, stream,
                     W1, W1bT, x, Wr, br, meta, top_i, top_w,
                     tok_of_row, wt_of_row, xb);
  hipLaunchKernelGGL(prefix_k, dim3(1), dim3(64), 0, stream, meta);
  hipLaunchKernelGGL(scatter_k, dim3(T_TOK / 256), dim3(256), 0, stream,
                     top_i, top_w, meta, row_of, tok_of_row, wt_of_row);
  hipLaunchKernelGGL(g1w2_k, dim3(6400), dim3(256), 0, stream,
                     xb, W1bT, W2, W2bT, b1, meta, wt_of_row, tok_of_row, hbuf);
  hipLaunchKernelGGL(gemm2_k, dim3((MAXR / 128) * (DIM / 128)), dim3(256), 0, stream,
                     hbuf, W2bT, b2, meta, wt_of_row, tok_of_row, out);
}

// Round 21
// 775.710 us; speedup vs baseline: 1.1613x; 1.1613x over previous
//
#include <hip/hip_runtime.h>
#include <cstdio>

// MoE top-2 FFN: B=4,S=2048,D=1024 -> T=8192 tokens; E=8, H=4096, K_TOP=2.
// Round 21: exact revert to r19 (776us best). r20's (256,5) capped VGPR at
// 48 < the ~60 this body needs -> spill (WRITE +7MB) + serialization, 388us.
// THIRD confirmation of the min-waves trap (r7/r9: 40 VGPR; r10: 56; r20: 48).
// (256,4) is the only safe launch bound for this GEMM body. Config: 128-pad
// (MAXR 17408), W2-transpose hidden inside GEMM1 dispatch, token-indirect A
// staging, BK=64 + 8-slot XOR swizzle, 4x4 XCD supertiles, atomic epilogue.

#define T_TOK 8192
#define DIM   1024
#define NEXP  8
#define HID   4096
#define MAXR  17408  // 16384 rows + 8 experts * up-to-127 pad, mult of 512

typedef float          f32x4   __attribute__((ext_vector_type(4)));
typedef short          bf16x8  __attribute__((ext_vector_type(8)));
typedef unsigned short u16x8   __attribute__((ext_vector_type(8)));
typedef unsigned short u16x4   __attribute__((ext_vector_type(4)));

static __device__ __forceinline__ unsigned short f2bf(float f) {
  unsigned int u = __builtin_bit_cast(unsigned int, f);
  u = (u + 0x7FFFu + ((u >> 16) & 1u)) >> 16;   // round-nearest-even (finite inputs)
  return (unsigned short)u;
}

// async global->LDS, 16B per lane; LDS dest = wave-uniform base + lane*16,
// global source is PER-LANE (enables token-indirect A staging)
static __device__ __forceinline__ void gl16(const void* g, void* l) {
  __builtin_amdgcn_global_load_lds(
      (const __attribute__((address_space(1))) unsigned int*)g,
      (__attribute__((address_space(3))) unsigned int*)l,
      16, 0, 0);
}

// ---------------- transpose + fp32->bf16, LDS-staged 128x128 tile ------------
static __device__ __forceinline__ void transpose_body(const float* __restrict__ W,
                                                      unsigned short* __restrict__ WT,
                                                      int R, int C, int bx, int by, int e,
                                                      unsigned int* tl) {
  int t = threadIdx.x;
  int r0 = by * 128, c0 = bx * 128;
  const float* src = W + (size_t)e * R * C + (size_t)r0 * C + c0;
  int cg = t & 31, ph = t >> 5;                  // col-group (x4 floats), p-high
  int c4 = cg * 4;
#pragma unroll
  for (int u = 0; u < 8; ++u) {
    int p = u * 8 + ph;                          // row-pair 0..63
    float4 f0 = *(const float4*)(src + (size_t)(2 * p) * C + c4);
    float4 f1 = *(const float4*)(src + (size_t)(2 * p + 1) * C + c4);
    unsigned int v0 = ((unsigned)f2bf(f1.x) << 16) | f2bf(f0.x);
    unsigned int v1 = ((unsigned)f2bf(f1.y) << 16) | f2bf(f0.y);
    unsigned int v2 = ((unsigned)f2bf(f1.z) << 16) | f2bf(f0.z);
    unsigned int v3 = ((unsigned)f2bf(f1.w) << 16) | f2bf(f0.w);
    *(uint4*)(tl + p * 132 + c4) = make_uint4(v0, v1, v2, v3);
  }
  __syncthreads();
  int rg = t & 15, ch = t >> 4;                  // row-group (x8 rows), col-high
  unsigned short* dst = WT + (size_t)e * R * C + (size_t)c0 * R + r0 + rg * 8;
#pragma unroll
  for (int u = 0; u < 8; ++u) {
    int c = ch + u * 16;
    u16x8 o;
#pragma unroll
    for (int j = 0; j < 4; ++j) {
      unsigned int v = tl[(rg * 4 + j) * 132 + c];
      o[2 * j]     = (unsigned short)(v & 0xffff);
      o[2 * j + 1] = (unsigned short)(v >> 16);
    }
    *(u16x8*)(dst + (size_t)c * R) = o;
  }
}

static __device__ __forceinline__ void router_body(int blk, const float* __restrict__ x,
                                                   const float* __restrict__ Wr,
                                                   const float* __restrict__ br,
                                                   int* __restrict__ meta,
                                                   int2* __restrict__ top_i,
                                                   float2* __restrict__ top_w) {
  int lane = threadIdx.x & 63;
  int wid  = threadIdx.x >> 6;
  int t = blk * 4 + wid;
  const float* xp = x + (size_t)t * DIM + lane * 16;
  float acc[NEXP];
#pragma unroll
  for (int e = 0; e < NEXP; ++e) acc[e] = 0.f;
#pragma unroll
  for (int j = 0; j < 16; j += 4) {
    float4 xv = *(const float4*)(xp + j);
    const float* wp = Wr + (size_t)(lane * 16 + j) * NEXP;
#pragma unroll
    for (int jj = 0; jj < 4; ++jj) {
      float xs = jj == 0 ? xv.x : jj == 1 ? xv.y : jj == 2 ? xv.z : xv.w;
      float4 w0 = *(const float4*)(wp + jj * NEXP);
      float4 w1 = *(const float4*)(wp + jj * NEXP + 4);
      acc[0] += xs * w0.x; acc[1] += xs * w0.y; acc[2] += xs * w0.z; acc[3] += xs * w0.w;
      acc[4] += xs * w1.x; acc[5] += xs * w1.y; acc[6] += xs * w1.z; acc[7] += xs * w1.w;
    }
  }
#pragma unroll
  for (int off = 32; off > 0; off >>= 1) {
#pragma unroll
    for (int e = 0; e < NEXP; ++e) acc[e] += __shfl_xor(acc[e], off);
  }
  if (lane == 0) {
    float l[NEXP];
#pragma unroll
    for (int e = 0; e < NEXP; ++e) l[e] = acc[e] + br[e];
    int e1 = 0;
#pragma unroll
    for (int e = 1; e < NEXP; ++e) if (l[e] > l[e1]) e1 = e;      // ties -> lower idx
    int e2 = (e1 == 0) ? 1 : 0;
#pragma unroll
    for (int e = 0; e < NEXP; ++e) if (e != e1 && l[e] > l[e2]) e2 = e;
    float g  = expf(l[e2] - l[e1]);              // softmax over top-2 == renorm of full softmax
    float w1 = 1.f / (1.f + g);
    top_i[t] = make_int2(e1, e2);
    top_w[t] = make_float2(w1, 1.f - w1);
    atomicAdd(&meta[e1], 1);
    atomicAdd(&meta[e2], 1);
  }
}

// ---- prep1: [0,2048) W1 transpose, [2048,4096) router, [4096,4164) fill,
//      [4164,6212) x->bf16 convert  (W2 transpose lives in g1w2_k) -----------
__global__ __launch_bounds__(256) void prep1_k(const float* __restrict__ W1,
                                               unsigned short* __restrict__ W1bT,
                                               const float* __restrict__ x,
                                               const float* __restrict__ Wr,
                                               const float* __restrict__ br,
                                               int* __restrict__ meta,
                                               int2* __restrict__ top_i,
                                               float2* __restrict__ top_w,
                                               int* __restrict__ tok_of_row,
                                               float* __restrict__ wt_of_row,
                                               unsigned short* __restrict__ xb) {
  __shared__ __align__(16) unsigned int tl[64 * 132];   // 33792 B
  int id = blockIdx.x;
  if (id < 2048) {                               // W1[e][D][H] -> [e][H][D]
    int rem = id & 255;                          // 8 by x 32 bx per expert
    transpose_body(W1, W1bT, DIM, HID, rem & 31, rem >> 5, id >> 8, tl);
  } else if (id < 4096) {
    router_body(id - 2048, x, Wr, br, meta, top_i, top_w);
  } else if (id < 4164) {
    int i = (id - 4096) * 256 + threadIdx.x;     // 68*256 == MAXR exactly
    if (i < MAXR) { tok_of_row[i] = 0; wt_of_row[i] = 0.f; }
  } else {                                       // xb = bf16(x), streaming
    size_t o = (size_t)(id - 4164) * 4096 + (size_t)threadIdx.x * 16;
#pragma unroll
    for (int h = 0; h < 2; ++h) {
      float4 a = *(const float4*)(x + o + h * 8);
      float4 b = *(const float4*)(x + o + h * 8 + 4);
      u16x8 v;
      v[0] = f2bf(a.x); v[1] = f2bf(a.y); v[2] = f2bf(a.z); v[3] = f2bf(a.w);
      v[4] = f2bf(b.x); v[5] = f2bf(b.y); v[6] = f2bf(b.z); v[7] = f2bf(b.w);
      *(u16x8*)(xb + o + h * 8) = v;
    }
  }
}

// -------- prefix: padded (x128) offsets ------------------------------------
__global__ void prefix_k(int* __restrict__ meta) {
  if (threadIdx.x == 0) {
    int s = 0;
#pragma unroll
    for (int e = 0; e < NEXP; ++e) {
      meta[16 + e] = s;                          // poff[e]
      s += (meta[e] + 127) & ~127;
    }
    meta[24] = s;                                // poff[8]
    meta[25] = s;                                // total_padded (<= MAXR always)
  }
}

// ---------------- scatter: token -> packed expert row ------------------------
__global__ __launch_bounds__(256) void scatter_k(const int2* __restrict__ top_i,
                                                 const float2* __restrict__ top_w,
                                                 int* __restrict__ meta,
                                                 int* __restrict__ row_of,
                                                 int* __restrict__ tok_of_row,
                                                 float* __restrict__ wt_of_row) {
  int t = blockIdx.x * 256 + threadIdx.x;
  int2  ei = top_i[t];
  float2 w = top_w[t];
  int p = atomicAdd(&meta[8 + ei.x], 1);
  int r = meta[16 + ei.x] + p;
  tok_of_row[r] = t; wt_of_row[r] = w.x; row_of[t * 2] = r;
  p = atomicAdd(&meta[8 + ei.y], 1);
  r = meta[16 + ei.y] + p;
  tok_of_row[r] = t; wt_of_row[r] = w.y; row_of[t * 2 + 1] = r;
}

// ---------------- GEMM body (r16-verbatim, id passed in) ---------------------
// A: bf16 (xb token-indirect for GEMM1, packed hbuf for GEMM2), gl16-staged
// into [128 rows][8 slots x 8] XOR-swizzled regions.  Bt: [E][NTOT][KTOT] bf16.
// 128x128 tile, BK=64, 4 waves, 32KB LDS, XCD-chunked 4x4 supertiles, pad-skip.
// EPI 0: h = bf16(gelu(acc+b1))   EPI 1: atomicAdd out[tok] += (acc+b2)*wt

template <int KTOT, int NTOT, int EPI, bool INDIR>
static __device__ __forceinline__ void gemm_body(int rawid,
                                                 const unsigned short* __restrict__ A,
                                                 const unsigned short* __restrict__ Bt,
                                                 const float* __restrict__ bias,
                                                 const int* __restrict__ meta,
                                                 const float* __restrict__ wt_of_row,
                                                 const int* __restrict__ tok_of_row,
                                                 void* __restrict__ Cout,
                                                 unsigned short* lds) {
  constexpr int NN  = NTOT / 128;                // 32 or 8
  constexpr int NXB = MAXR / 128;                // 136 row tiles
  constexpr int NWG = NXB * NN;                  // 4352 or 1088, both % 8 == 0
  constexpr int NSR = NXB / 4;                   // 34 row supertiles
  constexpr int NKT = KTOT / 64;                 // 16 or 64

  int id = (rawid & 7) * (NWG / 8) + (rawid >> 3);
  int sid = id >> 4, sub = id & 15;
  int row0 = ((sid % NSR) * 4 + (sub & 3)) * 128;
  int n0   = ((sid / NSR) * 4 + (sub >> 2)) * 128;
  if (row0 >= meta[25]) return;                  // beyond padded total (block-uniform)
  int e = 0;
  while (meta[17 + e] <= row0) ++e;              // tiles never straddle experts
  if (row0 - meta[16 + e] >= meta[e]) return;    // all-pad tile: skip (wt==0 gates EPI1)
  const unsigned short* Bp = Bt + (size_t)e * NTOT * KTOT;

  int tid = threadIdx.x;
  int lane = tid & 63, wid = tid >> 6;
  int wm = wid >> 1, wn = wid & 1;               // 2x2 waves, each owns 64x64 of C

  // staging (T2 write side): source col-slot s = (tid&7) ^ ((tid>>3)&7)
  int s = (tid & 7) ^ ((tid >> 3) & 7);
  const unsigned short* pA[4];
#pragma unroll
  for (int i = 0; i < 4; ++i) {
    int r = row0 + (tid >> 3) + i * 32;
    if constexpr (INDIR) {
      pA[i] = A + (size_t)tok_of_row[r] * KTOT + s * 8;   // pad rows: tok 0 (valid)
    } else {
      pA[i] = A + (size_t)r * KTOT + s * 8;
    }
  }
  const unsigned short* pB = Bp + (size_t)(n0 + (tid >> 3)) * KTOT + s * 8;

  // fragment reads (T2 read side): slot = (kk*4+g) ^ (am&7)
  int am = lane & 15, g = lane >> 4;
  int sw0 = ((0 * 4 + g) ^ (am & 7)) * 8;
  int sw1 = ((1 * 4 + g) ^ (am & 7)) * 8;
  int aRow = (wm * 64 + am) * 64;                // + i*1024 per fragment
  int bRow = 8192 + (wn * 64 + am) * 64;         // + j*1024 per fragment

  f32x4 acc[4][4];
#pragma unroll
  for (int i = 0; i < 4; ++i)
#pragma unroll
    for (int j = 0; j < 4; ++j) acc[i][j] = (f32x4){0.f, 0.f, 0.f, 0.f};

  for (int kt = 0; kt < NKT; ++kt) {
    __syncthreads();                             // prev compute done before overwrite
#pragma unroll
    for (int i = 0; i < 4; ++i) {
      gl16(pA[i] + kt * 64, lds + i * 2048 + tid * 8);
      gl16(pB + (size_t)(i * 32) * KTOT + kt * 64, lds + 8192 + i * 2048 + tid * 8);
    }
    __syncthreads();                             // compiler drains vmcnt before barrier
#pragma unroll
    for (int kk = 0; kk < 2; ++kk) {
      int sw = kk ? sw1 : sw0;
      bf16x8 af[4], bv[4];
#pragma unroll
      for (int i = 0; i < 4; ++i)
        af[i] = *(const bf16x8*)(lds + aRow + i * 1024 + sw);
#pragma unroll
      for (int j = 0; j < 4; ++j)
        bv[j] = *(const bf16x8*)(lds + bRow + j * 1024 + sw);
#pragma unroll
      for (int i = 0; i < 4; ++i)
#pragma unroll
        for (int j = 0; j < 4; ++j)
          acc[i][j] = __builtin_amdgcn_mfma_f32_16x16x32_bf16(af[i], bv[j], acc[i][j], 0, 0, 0);
    }
  }

  // epilogue.  C/D: col n = lane&15, row m = (lane>>4)*4 + reg  (validated)
  int rbase = row0 + wm * 64 + (g << 2);
  int nbase = n0 + wn * 64 + am;
  if constexpr (EPI == 0) {
    unsigned short* Hp = (unsigned short*)Cout;
    const float* bp = bias + (size_t)e * NTOT;
#pragma unroll
    for (int i = 0; i < 4; ++i)
#pragma unroll
      for (int j = 0; j < 4; ++j) {
        int n = nbase + j * 16;
        float bv = bp[n];
#pragma unroll
        for (int gg = 0; gg < 4; ++gg) {
          int m = rbase + i * 16 + gg;
          float v = acc[i][j][gg] + bv;
          v = 0.5f * v * (1.f + erff(v * 0.70710678118654752f));   // exact gelu
          Hp[(size_t)m * NTOT + n] = f2bf(v);
        }
      }
  } else {
    float* Op = (float*)Cout;
    const float* bp = bias + (size_t)e * NTOT;
#pragma unroll
    for (int i = 0; i < 4; ++i)
#pragma unroll
      for (int gg = 0; gg < 4; ++gg) {
        int m = rbase + i * 16 + gg;
        float wt = wt_of_row[m];
        if (wt != 0.f) {                         // pad rows excluded (wt exactly 0)
          float* orow = Op + (size_t)tok_of_row[m] * DIM;
#pragma unroll
          for (int j = 0; j < 4; ++j) {
            int n = nbase + j * 16;
            atomicAdd(orow + n, (acc[i][j][gg] + bp[n]) * wt);
          }
        }
      }
  }
}

// ---------------- fused GEMM1 + W2-transpose --------------------------------
// 6400 blocks: p%3==2 (p<6144) -> W2 transpose block p/3 (2048 of them,
// interleaved to co-schedule with GEMM1 and fill its stall bubbles);
// otherwise GEMM1 block (4352). Shared-mem union: 33792 B -> 4 blocks/CU.
__global__ __launch_bounds__(256, 4) void g1w2_k(const unsigned short* __restrict__ xb,
                                                 const unsigned short* __restrict__ W1bT,
                                                 const float* __restrict__ W2,
                                                 unsigned short* __restrict__ W2bT,
                                                 const float* __restrict__ b1,
                                                 const int* __restrict__ meta,
                                                 const float* __restrict__ wt_of_row,
                                                 const int* __restrict__ tok_of_row,
                                                 unsigned short* __restrict__ hbuf) {
  __shared__ __align__(16) unsigned char smem[64 * 132 * 4];   // 33792 B union
  int p = blockIdx.x;
  if (p < 6144 && (p % 3) == 2) {
    int id2 = p / 3;                             // 0..2047
    int rem = id2 & 255;                         // 32 by x 8 bx per expert
    transpose_body(W2, W2bT, HID, DIM, rem & 7, rem >> 3, id2 >> 8,
                   (unsigned int*)smem);
  } else {
    int rawid = (p < 6144) ? (p - p / 3) : (p - 2048);   // 0..4351, monotone
    gemm_body<DIM, HID, 0, true>(rawid, xb, W1bT, b1, meta, wt_of_row,
                                 tok_of_row, (void*)hbuf,
                                 (unsigned short*)smem);
  }
}

// ---------------- GEMM2 kernel: (256,4) — see min-waves trap note ------------
__global__ __launch_bounds__(256, 4) void gemm2_k(const unsigned short* __restrict__ hbuf,
                                                  const unsigned short* __restrict__ W2bT,
                                                  const float* __restrict__ b2,
                                                  const int* __restrict__ meta,
                                                  const float* __restrict__ wt_of_row,
                                                  const int* __restrict__ tok_of_row,
                                                  float* __restrict__ out) {
  __shared__ __align__(16) unsigned short lds[16384];   // 32 KiB
  gemm_body<HID, DIM, 1, false>((int)blockIdx.x, hbuf, W2bT, b2, meta,
                                wt_of_row, tok_of_row, (void*)out, lds);
}

extern "C" void kernel_launch(void* const* d_in, const int* in_sizes, int n_in,
                              void* d_out, int out_size, void* d_ws, size_t ws_size,
                              hipStream_t stream) {
  const float* x  = (const float*)d_in[0];
  const float* Wr = (const float*)d_in[1];
  const float* br = (const float*)d_in[2];
  const float* W1 = (const float*)d_in[3];
  const float* b1 = (const float*)d_in[4];
  const float* W2 = (const float*)d_in[5];
  const float* b2 = (const float*)d_in[6];
  float* out = (float*)d_out;

  char* base = (char*)d_ws;
  size_t off = 0;
  auto carve = [&](size_t bytes) -> void* {
    void* r = base + off;
    off = (off + bytes + 255) & ~(size_t)255;
    return r;
  };
  int*            meta       = (int*)carve(26 * 4);
  int2*           top_i      = (int2*)carve((size_t)T_TOK * 8);
  float2*         top_w      = (float2*)carve((size_t)T_TOK * 8);
  int*            row_of     = (int*)carve((size_t)T_TOK * 2 * 4);
  int*            tok_of_row = (int*)carve((size_t)MAXR * 4);
  float*          wt_of_row  = (float*)carve((size_t)MAXR * 4);
  unsigned short* xb         = (unsigned short*)carve((size_t)T_TOK * DIM * 2);
  unsigned short* W1bT       = (unsigned short*)carve((size_t)NEXP * DIM * HID * 2);
  unsigned short* W2bT       = (unsigned short*)carve((size_t)NEXP * DIM * HID * 2);
  unsigned short* hbuf       = (unsigned short*)carve((size_t)MAXR * HID * 2);
  if (off > ws_size) {
    fprintf(stderr, "kernel_launch: ws_size too small: need %zu have %zu\n", off, ws_size);
    return;
  }

  hipMemsetAsync(meta, 0, 26 * 4, stream);
  hipMemsetAsync(out, 0, (size_t)out_size * 4, stream);   // GEMM2 atomicAdds into out
  hipLaunchKernelGGL(prep1_k, dim3(6212), dim3(256), 0, stream,
                     W1, W1bT, x, Wr, br, meta, top_i, top_w,
                     tok_of_row, wt_of_row, xb);
  hipLaunchKernelGGL(prefix_k, dim3(1), dim3(64), 0, stream, meta);
  hipLaunchKernelGGL(scatter_k, dim3(T_TOK / 256), dim3(256), 0, stream,
                     top_i, top_w, meta, row_of, tok_of_row, wt_of_row);
  hipLaunchKernelGGL(g1w2_k, dim3(6400), dim3(256), 0, stream,
                     xb, W1bT, W2, W2bT, b1, meta, wt_of_row, tok_of_row, hbuf);
  hipLaunchKernelGGL(gemm2_k, dim3((MAXR / 128) * (DIM / 128)), dim3(256), 0, stream,
                     hbuf, W2bT, b2, meta, wt_of_row, tok_of_row, out);
}